// Round 13
// baseline (4115.203 us; speedup 1.0000x reference)
//
#include <hip/hip_runtime.h>
#include <hip/hip_bf16.h>

#define B_ 64
#define S_ 512
#define D_ 256
#define H_ 512

typedef __attribute__((ext_vector_type(8))) short bf16x8;
typedef __attribute__((ext_vector_type(4))) float f32x4;
typedef __attribute__((ext_vector_type(4))) unsigned int uint4v;
typedef unsigned short ushort_t;

__device__ __forceinline__ ushort_t f2bf(float f) {
    __hip_bfloat16 h = __float2bfloat16(f);   // RNE rounding
    return *reinterpret_cast<ushort_t*>(&h);
}
__device__ __forceinline__ float sigmoid_f(float x) { return 1.f / (1.f + __expf(-x)); }
__device__ __forceinline__ float tanh_f(float x) { return 1.f - 2.f / (__expf(2.f * x) + 1.f); }

// Swizzle W (4 gates, fp32 [D][H]) into B-frag-ordered bf16: Wsw[gate][ks][col][kk0..31],
// kk = q*8+j so a lane's 16B chunk at offset q*8 is its mfma B-operand registers.
__global__ void wsw_prep(const float* __restrict__ Wf, const float* __restrict__ Wi,
                         const float* __restrict__ Wo, const float* __restrict__ Wc,
                         ushort_t* __restrict__ Wsw)
{
    int idx = blockIdx.x * 256 + threadIdx.x;      // 4*8*512 = 16384 items
    if (idx >= 4 * 8 * 512) return;
    int col = idx & 511, ks = (idx >> 9) & 7, gate = idx >> 12;
    const float* Wg = (gate == 0) ? Wf : (gate == 1) ? Wi : (gate == 2) ? Wo : Wc;
    ushort_t* dst = Wsw + (size_t)idx * 32;
    #pragma unroll
    for (int kk = 0; kk < 32; ++kk)
        dst[kk] = f2bf(Wg[(ks * 32 + kk) * H_ + col]);
}

// grid: 64 blocks x 256 threads (4 waves); ranks 0..31 work, rest exit.
// PURE PER-WAVE STEP CHAIN — zero barriers / zero LDS in the loop.
// rank -> g = rank>>3 (batch rows g*16..+15), sb = rank&7; wave w owns 16 h-cols
// base = sb*64+w*16 for ALL 4 gates. U B-frags persistent (UF[4][16] = 256 VGPRs);
// W streamed from Wsw (L2) during the x-GEMM, which runs BEFORE the poll so it
// hides in the producer-tail wait. act + c/h update fully in-register (C-layout).
// h exchange: sc0 stores (XCD-uniform -> local L2; else sc0 sc1, R7-proven),
// flag = post-drain relaxed agent atomic store; poll = relaxed agent atomic loads
// (R10: plain sc0 loads are L1-stale; R9: RMW polls write-storm). x(t+1) loads are
// issued inside the store asm and drained with vmcnt(16): only the 4 h-stores
// (issued first, in-order retirement per m135) gate the flag.
__global__ __launch_bounds__(256, 1) void lstm_rec(
    const float* __restrict__ X,
    const float* __restrict__ bfp, const float* __restrict__ bip,
    const float* __restrict__ bop, const float* __restrict__ bcp,
    const float* __restrict__ Uf, const float* __restrict__ Ui,
    const float* __restrict__ Uo, const float* __restrict__ Uc,
    const float* __restrict__ Wfc, const ushort_t* __restrict__ Wsw,
    float* __restrict__ predP, ushort_t* __restrict__ hbufS,
    unsigned int* __restrict__ flags, unsigned int* __restrict__ xcdtab,
    float* __restrict__ outH, float* __restrict__ outC)
{
    __shared__ int meta[2];   // [0]=rank, [1]=uniform

    const int tid  = threadIdx.x;
    const int w    = tid >> 6;
    const int lane = tid & 63;
    const int q    = lane >> 4;
    const int m    = lane & 15;

    // ---- XCD self-assignment: wave 0 computes, LDS-broadcasts (R9-proven) ----
    if (w == 0) {
        unsigned int xcd;
        asm volatile("s_getreg_b32 %0, hwreg(HW_REG_XCC_ID)" : "=s"(xcd));
        xcd &= 15u;
        if (lane == 0)
            __hip_atomic_store(&xcdtab[blockIdx.x], xcd + 1u,
                               __ATOMIC_RELEASE, __HIP_MEMORY_SCOPE_AGENT);
        unsigned int entry;
        for (;;) {
            entry = __hip_atomic_load(&xcdtab[lane], __ATOMIC_ACQUIRE, __HIP_MEMORY_SCOPE_AGENT);
            if (__ballot(entry != 0u) == ~0ull) break;
            __builtin_amdgcn_s_sleep(1);
        }
        const unsigned int xcd_j = entry - 1u;
        const unsigned int key_j = (xcd_j << 8) | (unsigned int)lane;
        const unsigned int mykey = (xcd << 8) | (unsigned int)blockIdx.x;
        const int rank = __popcll(__ballot(key_j < mykey));
        const int c_lt = __popcll(__ballot(xcd_j < xcd));
        const int c_eq = __popcll(__ballot(xcd_j == xcd));
        const int gg   = rank >> 3;
        const bool uni = (c_lt <= gg * 8) && (gg * 8 + 8 <= c_lt + c_eq);
        if (lane == 0) { meta[0] = rank; meta[1] = uni ? 1 : 0; }
    }
    __syncthreads();
    const int  rank    = meta[0];
    const bool uniform = meta[1] != 0;
    if (rank >= 32) return;
    const int g    = rank >> 3;
    const int sb   = rank & 7;
    const int base = sb * 64 + w * 16;     // this wave's 16 h-cols (all 4 gates)

    const float* Us[4] = {Uf, Ui, Uo, Uc};
    const float* bs[4] = {bfp, bip, bop, bcp};

    // ---- one-time: U B-frags for all 4 gates (256 VGPRs) + biases ----
    bf16x8 UF[4][16];
    float  bias[4];
    #pragma unroll
    for (int g4 = 0; g4 < 4; ++g4) {
        bias[g4] = bs[g4][base + m];
        #pragma unroll
        for (int ks = 0; ks < 16; ++ks) {
            bf16x8 v;
            #pragma unroll
            for (int j = 0; j < 8; ++j)
                v[j] = (short)f2bf(Us[g4][(ks * 32 + q * 8 + j) * H_ + base + m]);
            UF[g4][ks] = v;
        }
    }
    const float wfc_m = Wfc[base + m];
    float cst[4] = {0.f, 0.f, 0.f, 0.f};

    unsigned int* flagsG = flags + g * 32;
    const int myflag = sb * 4 + w;

    // per-lane X pointer: A-frag row = batch row g*16+m, k-offset q*8
    const float* xptr = X + ((size_t)(g * 16 + m) * S_) * D_ + q * 8;

    // ---- preamble: x(0) A-frag loads ----
    float4 xf[16];
    #pragma unroll
    for (int ks = 0; ks < 8; ++ks) {
        xf[2 * ks]     = *(const float4*)(xptr + ks * 32);
        xf[2 * ks + 1] = *(const float4*)(xptr + ks * 32 + 4);
    }

    for (int t = 0; t < S_; ++t) {
        // ---- x-part (h-independent; runs while producers finish) ----
        bf16x8 xb[8];
        #pragma unroll
        for (int ks = 0; ks < 8; ++ks) {
            bf16x8 v;
            v[0] = (short)f2bf(xf[2 * ks].x);     v[1] = (short)f2bf(xf[2 * ks].y);
            v[2] = (short)f2bf(xf[2 * ks].z);     v[3] = (short)f2bf(xf[2 * ks].w);
            v[4] = (short)f2bf(xf[2 * ks + 1].x); v[5] = (short)f2bf(xf[2 * ks + 1].y);
            v[6] = (short)f2bf(xf[2 * ks + 1].z); v[7] = (short)f2bf(xf[2 * ks + 1].w);
            xb[ks] = v;
        }
        f32x4 acc[4];
        #pragma unroll
        for (int g4 = 0; g4 < 4; ++g4)
            acc[g4] = (f32x4){bias[g4], bias[g4], bias[g4], bias[g4]};
        #pragma unroll
        for (int ks = 0; ks < 8; ++ks) {
            #pragma unroll
            for (int g4 = 0; g4 < 4; ++g4) {
                bf16x8 wv = *(const bf16x8*)(Wsw + ((size_t)((g4 * 8 + ks) * 512 + base + m)) * 32 + q * 8);
                acc[g4] = __builtin_amdgcn_mfma_f32_16x16x32_bf16(xb[ks], wv, acc[g4], 0, 0, 0);
            }
        }

        // ---- poll: all 32 producer waves of this group posted h(t) ----
        if (t > 0) {
            const unsigned int tgt = (unsigned int)t;
            for (;;) {
                unsigned int f = __hip_atomic_load(&flagsG[lane & 31],
                                                   __ATOMIC_RELAXED, __HIP_MEMORY_SCOPE_AGENT);
                if (__ballot(f >= tgt) == ~0ull) break;
                __builtin_amdgcn_s_sleep(1);
            }
        }

        // ---- h A-frag: 16 x 16B direct loads (L2-local when uniform) ----
        const ushort_t* hp = hbufS + ((size_t)((t % 3) * B_ + g * 16 + m)) * H_ + q * 8;
        uint4v hf[16];
        if (uniform) {
            asm volatile(
                "global_load_dwordx4 %0,  %16, off offset:0   sc0\n\t"
                "global_load_dwordx4 %1,  %16, off offset:64  sc0\n\t"
                "global_load_dwordx4 %2,  %16, off offset:128 sc0\n\t"
                "global_load_dwordx4 %3,  %16, off offset:192 sc0\n\t"
                "global_load_dwordx4 %4,  %16, off offset:256 sc0\n\t"
                "global_load_dwordx4 %5,  %16, off offset:320 sc0\n\t"
                "global_load_dwordx4 %6,  %16, off offset:384 sc0\n\t"
                "global_load_dwordx4 %7,  %16, off offset:448 sc0\n\t"
                "global_load_dwordx4 %8,  %16, off offset:512 sc0\n\t"
                "global_load_dwordx4 %9,  %16, off offset:576 sc0\n\t"
                "global_load_dwordx4 %10, %16, off offset:640 sc0\n\t"
                "global_load_dwordx4 %11, %16, off offset:704 sc0\n\t"
                "global_load_dwordx4 %12, %16, off offset:768 sc0\n\t"
                "global_load_dwordx4 %13, %16, off offset:832 sc0\n\t"
                "global_load_dwordx4 %14, %16, off offset:896 sc0\n\t"
                "global_load_dwordx4 %15, %16, off offset:960 sc0\n\t"
                "s_waitcnt vmcnt(0)"
                : "=v"(hf[0]), "=v"(hf[1]), "=v"(hf[2]), "=v"(hf[3]),
                  "=v"(hf[4]), "=v"(hf[5]), "=v"(hf[6]), "=v"(hf[7]),
                  "=v"(hf[8]), "=v"(hf[9]), "=v"(hf[10]), "=v"(hf[11]),
                  "=v"(hf[12]), "=v"(hf[13]), "=v"(hf[14]), "=v"(hf[15])
                : "v"(hp) : "memory");
        } else {
            asm volatile(
                "global_load_dwordx4 %0,  %16, off offset:0   sc0 sc1\n\t"
                "global_load_dwordx4 %1,  %16, off offset:64  sc0 sc1\n\t"
                "global_load_dwordx4 %2,  %16, off offset:128 sc0 sc1\n\t"
                "global_load_dwordx4 %3,  %16, off offset:192 sc0 sc1\n\t"
                "global_load_dwordx4 %4,  %16, off offset:256 sc0 sc1\n\t"
                "global_load_dwordx4 %5,  %16, off offset:320 sc0 sc1\n\t"
                "global_load_dwordx4 %6,  %16, off offset:384 sc0 sc1\n\t"
                "global_load_dwordx4 %7,  %16, off offset:448 sc0 sc1\n\t"
                "global_load_dwordx4 %8,  %16, off offset:512 sc0 sc1\n\t"
                "global_load_dwordx4 %9,  %16, off offset:576 sc0 sc1\n\t"
                "global_load_dwordx4 %10, %16, off offset:640 sc0 sc1\n\t"
                "global_load_dwordx4 %11, %16, off offset:704 sc0 sc1\n\t"
                "global_load_dwordx4 %12, %16, off offset:768 sc0 sc1\n\t"
                "global_load_dwordx4 %13, %16, off offset:832 sc0 sc1\n\t"
                "global_load_dwordx4 %14, %16, off offset:896 sc0 sc1\n\t"
                "global_load_dwordx4 %15, %16, off offset:960 sc0 sc1\n\t"
                "s_waitcnt vmcnt(0)"
                : "=v"(hf[0]), "=v"(hf[1]), "=v"(hf[2]), "=v"(hf[3]),
                  "=v"(hf[4]), "=v"(hf[5]), "=v"(hf[6]), "=v"(hf[7]),
                  "=v"(hf[8]), "=v"(hf[9]), "=v"(hf[10]), "=v"(hf[11]),
                  "=v"(hf[12]), "=v"(hf[13]), "=v"(hf[14]), "=v"(hf[15])
                : "v"(hp) : "memory");
        }

        // ---- h.U MFMAs (K = 512) ----
        #pragma unroll
        for (int ks = 0; ks < 16; ++ks) {
            bf16x8 a;
            __builtin_memcpy(&a, &hf[ks], 16);
            #pragma unroll
            for (int g4 = 0; g4 < 4; ++g4)
                acc[g4] = __builtin_amdgcn_mfma_f32_16x16x32_bf16(a, UF[g4][ks], acc[g4], 0, 0, 0);
        }

        // ---- activations + state update, in-register (C-layout) ----
        float hj[4];
        #pragma unroll
        for (int j = 0; j < 4; ++j) {
            float fv = sigmoid_f(acc[0][j]);
            float iv = sigmoid_f(acc[1][j]);
            float ov = sigmoid_f(acc[2][j]);
            float ch = tanh_f(acc[3][j]);
            cst[j] = fv * cst[j] + iv * ch;
            hj[j]  = ov * tanh_f(cst[j]);
        }

        if (t < S_ - 1) {
            // h stores (rows g*16+q*4+j, col base+m) + x(t+1) loads + partial drain:
            // vmcnt(16) retires exactly the 4 stores (issued first, in-order).
            ushort_t* hsb = hbufS + ((size_t)(((t + 1) % 3) * B_ + g * 16 + q * 4)) * H_ + base + m;
            const float* xnext = xptr + (size_t)(t + 1) * D_;
            unsigned int h0 = f2bf(hj[0]), h1 = f2bf(hj[1]), h2 = f2bf(hj[2]), h3 = f2bf(hj[3]);
            uint4v xv[16];
            if (uniform) {
                asm volatile(
                    "global_store_short %16, %17, off offset:0    sc0\n\t"
                    "global_store_short %16, %18, off offset:1024 sc0\n\t"
                    "global_store_short %16, %19, off offset:2048 sc0\n\t"
                    "global_store_short %16, %20, off offset:3072 sc0\n\t"
                    "global_load_dwordx4 %0,  %21, off offset:0\n\t"
                    "global_load_dwordx4 %1,  %21, off offset:16\n\t"
                    "global_load_dwordx4 %2,  %21, off offset:128\n\t"
                    "global_load_dwordx4 %3,  %21, off offset:144\n\t"
                    "global_load_dwordx4 %4,  %21, off offset:256\n\t"
                    "global_load_dwordx4 %5,  %21, off offset:272\n\t"
                    "global_load_dwordx4 %6,  %21, off offset:384\n\t"
                    "global_load_dwordx4 %7,  %21, off offset:400\n\t"
                    "global_load_dwordx4 %8,  %21, off offset:512\n\t"
                    "global_load_dwordx4 %9,  %21, off offset:528\n\t"
                    "global_load_dwordx4 %10, %21, off offset:640\n\t"
                    "global_load_dwordx4 %11, %21, off offset:656\n\t"
                    "global_load_dwordx4 %12, %21, off offset:768\n\t"
                    "global_load_dwordx4 %13, %21, off offset:784\n\t"
                    "global_load_dwordx4 %14, %21, off offset:896\n\t"
                    "global_load_dwordx4 %15, %21, off offset:912\n\t"
                    "s_waitcnt vmcnt(16)"
                    : "=v"(xv[0]), "=v"(xv[1]), "=v"(xv[2]), "=v"(xv[3]),
                      "=v"(xv[4]), "=v"(xv[5]), "=v"(xv[6]), "=v"(xv[7]),
                      "=v"(xv[8]), "=v"(xv[9]), "=v"(xv[10]), "=v"(xv[11]),
                      "=v"(xv[12]), "=v"(xv[13]), "=v"(xv[14]), "=v"(xv[15])
                    : "v"(hsb), "v"(h0), "v"(h1), "v"(h2), "v"(h3), "v"(xnext)
                    : "memory");
            } else {
                asm volatile(
                    "global_store_short %16, %17, off offset:0    sc0 sc1\n\t"
                    "global_store_short %16, %18, off offset:1024 sc0 sc1\n\t"
                    "global_store_short %16, %19, off offset:2048 sc0 sc1\n\t"
                    "global_store_short %16, %20, off offset:3072 sc0 sc1\n\t"
                    "global_load_dwordx4 %0,  %21, off offset:0\n\t"
                    "global_load_dwordx4 %1,  %21, off offset:16\n\t"
                    "global_load_dwordx4 %2,  %21, off offset:128\n\t"
                    "global_load_dwordx4 %3,  %21, off offset:144\n\t"
                    "global_load_dwordx4 %4,  %21, off offset:256\n\t"
                    "global_load_dwordx4 %5,  %21, off offset:272\n\t"
                    "global_load_dwordx4 %6,  %21, off offset:384\n\t"
                    "global_load_dwordx4 %7,  %21, off offset:400\n\t"
                    "global_load_dwordx4 %8,  %21, off offset:512\n\t"
                    "global_load_dwordx4 %9,  %21, off offset:528\n\t"
                    "global_load_dwordx4 %10, %21, off offset:640\n\t"
                    "global_load_dwordx4 %11, %21, off offset:656\n\t"
                    "global_load_dwordx4 %12, %21, off offset:768\n\t"
                    "global_load_dwordx4 %13, %21, off offset:784\n\t"
                    "global_load_dwordx4 %14, %21, off offset:896\n\t"
                    "global_load_dwordx4 %15, %21, off offset:912\n\t"
                    "s_waitcnt vmcnt(16)"
                    : "=v"(xv[0]), "=v"(xv[1]), "=v"(xv[2]), "=v"(xv[3]),
                      "=v"(xv[4]), "=v"(xv[5]), "=v"(xv[6]), "=v"(xv[7]),
                      "=v"(xv[8]), "=v"(xv[9]), "=v"(xv[10]), "=v"(xv[11]),
                      "=v"(xv[12]), "=v"(xv[13]), "=v"(xv[14]), "=v"(xv[15])
                    : "v"(hsb), "v"(h0), "v"(h1), "v"(h2), "v"(h3), "v"(xnext)
                    : "memory");
            }
            if (lane == 0) {
                __hip_atomic_store(&flagsG[myflag], (unsigned int)(t + 1),
                                   __ATOMIC_RELAXED, __HIP_MEMORY_SCOPE_AGENT);
            }
            #pragma unroll
            for (int i = 0; i < 16; ++i)
                __builtin_memcpy(&xf[i], &xv[i], 16);
        } else {
            #pragma unroll
            for (int j = 0; j < 4; ++j) {
                outH[(size_t)(g * 16 + q * 4 + j) * H_ + base + m] = hj[j];
                outC[(size_t)(g * 16 + q * 4 + j) * H_ + base + m] = cst[j];
            }
        }

        // ---- pred partials (off-chain): reduce over m, plain stores ----
        float pv[4];
        #pragma unroll
        for (int j = 0; j < 4; ++j) pv[j] = hj[j] * wfc_m;
        #pragma unroll
        for (int j = 0; j < 4; ++j) {
            pv[j] += __shfl_xor(pv[j], 1);
            pv[j] += __shfl_xor(pv[j], 2);
            pv[j] += __shfl_xor(pv[j], 4);
            pv[j] += __shfl_xor(pv[j], 8);
        }
        if (m == 0) {
            #pragma unroll
            for (int j = 0; j < 4; ++j)
                predP[((size_t)myflag * B_ + g * 16 + q * 4 + j) * S_ + t] = pv[j];
        }
    }
}

__global__ void pred_fin(const float* __restrict__ predP,
                         const float* __restrict__ bfc,
                         float* __restrict__ out)
{
    int i = blockIdx.x * blockDim.x + threadIdx.x;
    if (i < B_ * S_) {
        float v = bfc[0];
        #pragma unroll
        for (int sl = 0; sl < 32; ++sl)
            v += predP[(size_t)sl * B_ * S_ + i];
        out[i] = v;
    }
}

extern "C" void kernel_launch(void* const* d_in, const int* in_sizes, int n_in,
                              void* d_out, int out_size, void* d_ws, size_t ws_size,
                              hipStream_t stream) {
    const float* X   = (const float*)d_in[0];
    const float* Wf  = (const float*)d_in[1];
    const float* Wi  = (const float*)d_in[2];
    const float* Wo  = (const float*)d_in[3];
    const float* Wc  = (const float*)d_in[4];
    const float* bfp = (const float*)d_in[5];
    const float* bip = (const float*)d_in[6];
    const float* bop = (const float*)d_in[7];
    const float* bcp = (const float*)d_in[8];
    const float* Uf  = (const float*)d_in[9];
    const float* Ui  = (const float*)d_in[10];
    const float* Uo  = (const float*)d_in[11];
    const float* Uc  = (const float*)d_in[12];
    const float* Wfc = (const float*)d_in[13];
    const float* bfc = (const float*)d_in[14];

    // ws layout: hbuf bf16 [3][64][512] @0 (196608) | flags @196608 (1KB)
    //            | xcdtab @197632 (256B) | Wsw bf16 @262144 (1MB)
    //            | predP fp32 [32][64][512] @1310720 (4MB)
    ushort_t*     hbufS  = (ushort_t*)d_ws;
    unsigned int* flags  = (unsigned int*)((char*)d_ws + 196608);
    unsigned int* xcdtab = (unsigned int*)((char*)d_ws + 197632);
    ushort_t*     Wsw    = (ushort_t*)((char*)d_ws + 262144);
    float*        predP  = (float*)((char*)d_ws + 1310720);

    hipMemsetAsync(d_ws, 0, 197888, stream);   // zero hbuf slot0, flags, xcdtab

    float* out = (float*)d_out;
    wsw_prep<<<64, 256, 0, stream>>>(Wf, Wi, Wo, Wc, Wsw);
    lstm_rec<<<64, 256, 0, stream>>>(X, bfp, bip, bop, bcp,
                                     Uf, Ui, Uo, Uc, Wfc, Wsw,
                                     predP, hbufS, flags, xcdtab,
                                     out + 32768, out + 65536);
    pred_fin<<<128, 256, 0, stream>>>(predP, bfc, out);
}